// Round 10
// baseline (397.401 us; speedup 1.0000x reference)
//
#include <hip/hip_runtime.h>
#include <math.h>

constexpr int NB = 2;
constexpr int NS = 2048;
constexpr int ND = 1024;
constexpr int NH = 16;
constexpr int NDK = 64;

typedef __attribute__((ext_vector_type(8))) short short8;
typedef __attribute__((ext_vector_type(4))) float floatx4;

__device__ inline unsigned short f2bf(float x) {
    unsigned u = __builtin_bit_cast(unsigned, x);
    u += 0x7fffu + ((u >> 16) & 1u);          // RNE
    return (unsigned short)(u >> 16);
}

__device__ inline uint4 pack8(float4 a, float4 b) {
    unsigned short t[8] = {f2bf(a.x), f2bf(a.y), f2bf(a.z), f2bf(a.w),
                           f2bf(b.x), f2bf(b.y), f2bf(b.z), f2bf(b.w)};
    return *(uint4*)t;
}

#define GLOAD_LDS16(g, l) __builtin_amdgcn_global_load_lds( \
    (const __attribute__((address_space(1))) void*)(g),     \
    (__attribute__((address_space(3))) void*)(l), 16, 0, 0)

// scale folded into Q projection: exp(s/8) == exp2(s * 0.125 * log2(e))
#define QSCALE 0.18033688f

// ---------------------------------------------------------------------------
// fp32 -> bf16 convert for Wo ONLY (Q/K/V inputs + Wq/Wk/Wv are now consumed
// as f32 directly by gemm_qkv's reg-staged conversion). 1M elems exactly.
// ---------------------------------------------------------------------------
__global__ __launch_bounds__(256) void cvt_w(
    const float* __restrict__ s, unsigned short* __restrict__ d)
{
    int i = (blockIdx.x * 256 + threadIdx.x) * 8;
    float4 a = *(const float4*)(s + i);
    float4 b = *(const float4*)(s + i + 4);
    *(uint4*)(d + i) = pack8(a, b);
}

// ---------------------------------------------------------------------------
// Fused QKV projection — 256x256 tile, BK=64, 8-phase schedule, f32 sources.
// Staging is reg-staged fused convert: per phase, issue 4 global f32 loads
// (2 slots) BEFORE the phase barrier, run the 16-MFMA cluster (covers L2
// latency; X/W tiles are L2-resident per XCD: the 4 blocks sharing a tile
// share an XCD), then pack8 -> 2x ds_write_b128, lgkmcnt(0), end barrier.
// No cross-phase vmem counting needed: each phase's loads are consumed in
// the same phase; ds_writes are sealed by the phase-end barrier; every
// buffer's last ds_read drains (first lgkm(0) of its phase) >=2 barriers
// before its rewrite. bf16 values are BIT-IDENTICAL to the old cvt_all path
// (same f2bf), so output must match exactly.
// ---------------------------------------------------------------------------
template<int QA, int QB>
__device__ __forceinline__ void mfma_quad(
    floatx4 (&acc)[8][4], const short8 (&ta)[4][2], const short8 (&tb)[2][2][2])
{
#pragma unroll
    for (int ii = 0; ii < 4; ++ii)
#pragma unroll
        for (int jj = 0; jj < 2; ++jj) {
            acc[QA * 4 + ii][QB * 2 + jj] = __builtin_amdgcn_mfma_f32_16x16x32_bf16(
                ta[ii][0], tb[QB][jj][0], acc[QA * 4 + ii][QB * 2 + jj], 0, 0, 0);
            acc[QA * 4 + ii][QB * 2 + jj] = __builtin_amdgcn_mfma_f32_16x16x32_bf16(
                ta[ii][1], tb[QB][jj][1], acc[QA * 4 + ii][QB * 2 + jj], 0, 0, 0);
        }
}

__global__ __launch_bounds__(512, 2) void gemm_qkv(
    const float* __restrict__ Xq, const float* __restrict__ Xk,
    const float* __restrict__ Xv,
    const float* __restrict__ Wq, const float* __restrict__ Wk,
    const float* __restrict__ Wv,
    const float* __restrict__ bq, const float* __restrict__ bk,
    const float* __restrict__ bv,
    unsigned short* __restrict__ Cq, unsigned short* __restrict__ Ck,
    unsigned short* __restrict__ Cv)
{
    __shared__ unsigned short As[2][256 * 64];
    __shared__ unsigned short Bs[2][256 * 64];

    const int tid = threadIdx.x, w = tid >> 6, lane = tid & 63;
    const int lo = lane & 15, quad = lane >> 4;
    const int bid = blockIdx.x;
    const int seg = bid >> 6;          // 0,1,2 (64 blocks each)
    const int idx = bid & 63;
    const int xcd = idx & 7;
    const int t8  = idx >> 3;          // 0..7
    const int K = ND;

    int bm, bn;
    const float *A, *Bw;
    const float* bias;
    if (seg == 2) {
        bm = t8 & 3; bn = (t8 >> 2) * 8 + xcd;
        A = Wv; Bw = Xv; bias = bv;
    } else {
        bn = t8 & 3; bm = (t8 >> 2) * 8 + xcd;
        if (seg == 1) { A = Xk; Bw = Wk; bias = bk; }
        else          { A = Xq; Bw = Wq; bias = bq; }
    }

    const int WM = (w >> 2) * 128, WN = (w & 3) * 64;

    // staging geometry: slot s_, thread tid -> LDS row s_*64 + (tid>>3),
    // pos tid&7 holding global chunk (tid&7)^(row&7) (8 bf16 elems = 16B).
    const int srow = tid >> 3;                               // 0..63
    const int sgo  = ((tid & 7) ^ (srow & 7)) * 8;           // element offset
    const float* Asrc = A  + (size_t)(bm * 256 + srow) * K + sgo;
    const float* Bsrc = Bw + (size_t)(bn * 256 + srow) * K + sgo;

#define LDA(t_, s_, a_, b_) { const float* p_ = Asrc + (size_t)(s_) * 64 * K + (t_) * 64; \
    a_ = *(const float4*)(p_); b_ = *(const float4*)(p_ + 4); }
#define LDB(t_, s_, a_, b_) { const float* p_ = Bsrc + (size_t)(s_) * 64 * K + (t_) * 64; \
    a_ = *(const float4*)(p_); b_ = *(const float4*)(p_ + 4); }
#define WRA(bf_, s_, a_, b_) *(uint4*)(&As[bf_][(s_) * 4096 + tid * 8]) = pack8(a_, b_);
#define WRB(bf_, s_, a_, b_) *(uint4*)(&Bs[bf_][(s_) * 4096 + tid * 8]) = pack8(a_, b_);

    const int rp0 = ((quad) ^ (lo & 7)) * 8;        // kstep 0 chunk pos
    const int rp1 = ((4 + quad) ^ (lo & 7)) * 8;    // kstep 1 chunk pos

    short8 ta[4][2], tb[2][2][2];

#define RDA(bf_, qa_) { _Pragma("unroll") \
    for (int ii = 0; ii < 4; ++ii) { \
        const unsigned short* p_ = &As[bf_][(WM + (qa_) * 64 + ii * 16 + lo) * 64]; \
        ta[ii][0] = *(const short8*)(p_ + rp0); \
        ta[ii][1] = *(const short8*)(p_ + rp1); } }
#define RDB(bf_, qb_) { _Pragma("unroll") \
    for (int jj = 0; jj < 2; ++jj) { \
        const unsigned short* p_ = &Bs[bf_][(WN + (qb_) * 32 + jj * 16 + lo) * 64]; \
        tb[qb_][jj][0] = *(const short8*)(p_ + rp0); \
        tb[qb_][jj][1] = *(const short8*)(p_ + rp1); } }

    // phase sync: pin issued loads/ds_reads before the start barrier; drain
    // own ds_reads after it; fence MFMA cluster; writes drained before end.
#define PH_IN  __builtin_amdgcn_sched_barrier(0); \
    __builtin_amdgcn_s_barrier(); \
    asm volatile("s_waitcnt lgkmcnt(0)" ::: "memory"); \
    __builtin_amdgcn_sched_barrier(0); \
    __builtin_amdgcn_s_setprio(1);
#define PH_MID __builtin_amdgcn_s_setprio(0); \
    __builtin_amdgcn_sched_barrier(0);
#define PH_OUT asm volatile("s_waitcnt lgkmcnt(0)" ::: "memory"); \
    __builtin_amdgcn_sched_barrier(0); \
    __builtin_amdgcn_s_barrier();

    floatx4 acc[8][4];
#pragma unroll
    for (int i = 0; i < 8; ++i)
#pragma unroll
        for (int j = 0; j < 4; ++j) acc[i][j] = (floatx4){0.f, 0.f, 0.f, 0.f};

    // prologue: B(buf0)<-t0, A(buf0)<-t0, B(buf1)<-t1 (reg-staged convert;
    // compiler inserts the vmcnt waits before each pack8 use)
    {
        float4 f0, f1, f2, f3, f4, f5, f6, f7;
        LDB(0, 0, f0, f1); LDB(0, 1, f2, f3); LDB(0, 2, f4, f5); LDB(0, 3, f6, f7);
        WRB(0, 0, f0, f1); WRB(0, 1, f2, f3); WRB(0, 2, f4, f5); WRB(0, 3, f6, f7);
        LDA(0, 0, f0, f1); LDA(0, 1, f2, f3); LDA(0, 2, f4, f5); LDA(0, 3, f6, f7);
        WRA(0, 0, f0, f1); WRA(0, 1, f2, f3); WRA(0, 2, f4, f5); WRA(0, 3, f6, f7);
        LDB(1, 0, f0, f1); LDB(1, 1, f2, f3); LDB(1, 2, f4, f5); LDB(1, 3, f6, f7);
        WRB(1, 0, f0, f1); WRB(1, 1, f2, f3); WRB(1, 2, f4, f5); WRB(1, 3, f6, f7);
        asm volatile("s_waitcnt lgkmcnt(0)" ::: "memory");
        __builtin_amdgcn_s_barrier();
    }

    constexpr int NIT = ND / 128;   // 8 iterations, 2 K-tiles each
#pragma unroll 1
    for (int it = 0; it < NIT; ++it) {
        const bool nl = (it < NIT - 1);
        const int t1 = 2 * it + 1, t2 = 2 * it + 2, t3 = 2 * it + 3;

        // p0: buf0 (0,0); stage A(buf1)<-t1 slots 0,1
        {
            float4 f0, f1, f2, f3;
            RDA(0, 0); RDB(0, 0);
            LDA(t1, 0, f0, f1); LDA(t1, 1, f2, f3);
            PH_IN; mfma_quad<0, 0>(acc, ta, tb); PH_MID;
            WRA(1, 0, f0, f1); WRA(1, 1, f2, f3);
            PH_OUT;
        }
        // p1: buf0 (0,1); stage A(buf1)<-t1 slots 2,3
        {
            float4 f0, f1, f2, f3;
            RDB(0, 1);
            LDA(t1, 2, f0, f1); LDA(t1, 3, f2, f3);
            PH_IN; mfma_quad<0, 1>(acc, ta, tb); PH_MID;
            WRA(1, 2, f0, f1); WRA(1, 3, f2, f3);
            PH_OUT;
        }
        // p2: buf0 (1,1); stage B(buf0)<-t2 slots 0,1  [B(buf0) freed p1]
        {
            float4 f0, f1, f2, f3;
            RDA(0, 1);
            if (nl) { LDB(t2, 0, f0, f1); LDB(t2, 1, f2, f3); }
            PH_IN; mfma_quad<1, 1>(acc, ta, tb); PH_MID;
            if (nl) { WRB(0, 0, f0, f1); WRB(0, 1, f2, f3); }
            PH_OUT;
        }
        // p3: buf0 (1,0); stage B(buf0)<-t2 slots 2,3
        {
            float4 f0, f1, f2, f3;
            if (nl) { LDB(t2, 2, f0, f1); LDB(t2, 3, f2, f3); }
            PH_IN; mfma_quad<1, 0>(acc, ta, tb); PH_MID;
            if (nl) { WRB(0, 2, f0, f1); WRB(0, 3, f2, f3); }
            PH_OUT;
        }
        // p4: buf1 (0,0); stage A(buf0)<-t2 slots 0,1  [A(buf0) freed p2]
        {
            float4 f0, f1, f2, f3;
            RDA(1, 0); RDB(1, 0);
            if (nl) { LDA(t2, 0, f0, f1); LDA(t2, 1, f2, f3); }
            PH_IN; mfma_quad<0, 0>(acc, ta, tb); PH_MID;
            if (nl) { WRA(0, 0, f0, f1); WRA(0, 1, f2, f3); }
            PH_OUT;
        }
        // p5: buf1 (0,1); stage A(buf0)<-t2 slots 2,3
        {
            float4 f0, f1, f2, f3;
            RDB(1, 1);
            if (nl) { LDA(t2, 2, f0, f1); LDA(t2, 3, f2, f3); }
            PH_IN; mfma_quad<0, 1>(acc, ta, tb); PH_MID;
            if (nl) { WRA(0, 2, f0, f1); WRA(0, 3, f2, f3); }
            PH_OUT;
        }
        // p6: buf1 (1,1); stage B(buf1)<-t3 slots 0,1  [B(buf1) freed p5]
        {
            float4 f0, f1, f2, f3;
            RDA(1, 1);
            if (nl) { LDB(t3, 0, f0, f1); LDB(t3, 1, f2, f3); }
            PH_IN; mfma_quad<1, 1>(acc, ta, tb); PH_MID;
            if (nl) { WRB(1, 0, f0, f1); WRB(1, 1, f2, f3); }
            PH_OUT;
        }
        // p7: buf1 (1,0); stage B(buf1)<-t3 slots 2,3
        {
            float4 f0, f1, f2, f3;
            if (nl) { LDB(t3, 2, f0, f1); LDB(t3, 3, f2, f3); }
            PH_IN; mfma_quad<1, 0>(acc, ta, tb); PH_MID;
            if (nl) { WRB(1, 2, f0, f1); WRB(1, 3, f2, f3); }
            PH_OUT;
        }
    }

#undef LDA
#undef LDB
#undef WRA
#undef WRB
#undef RDA
#undef RDB
#undef PH_IN
#undef PH_MID
#undef PH_OUT

    if (seg < 2) {
        unsigned short* C = seg ? Ck : Cq;
        const float scale = seg ? 1.f : QSCALE;
#pragma unroll
        for (int j = 0; j < 4; ++j) {
            const int col = bn * 256 + WN + j * 16 + lo;
            const float bb = bias[col];
#pragma unroll
            for (int i = 0; i < 8; ++i)
#pragma unroll
                for (int r = 0; r < 4; ++r) {
                    const int row = bm * 256 + WM + i * 16 + quad * 4 + r;
                    C[(size_t)row * ND + col] = f2bf((acc[i][j][r] + bb) * scale);
                }
        }
    } else {
        // rows = d (0..1023), cols = tokens; write vt[(b*ND + d)*NS + s]
#pragma unroll
        for (int i = 0; i < 8; ++i)
#pragma unroll
            for (int r = 0; r < 4; ++r) {
                const int row = bm * 256 + WM + i * 16 + quad * 4 + r;
                const float bb = bias[row];
#pragma unroll
                for (int j = 0; j < 4; ++j) {
                    const int col = bn * 256 + WN + j * 16 + lo;
                    const int b = col >> 11, s = col & (NS - 1);
                    Cv[(size_t)(b * ND + row) * NS + s] = f2bf(acc[i][j][r] + bb);
                }
            }
    }
}

// ---------------------------------------------------------------------------
// MFMA flash attention, K-split x2. 512 threads = 8 waves, 256 q-rows/block,
// grid 512 = 2 blocks/CU. Double-buffered K/V staging with counted vmcnt(2)
// + raw barriers (verified R8 version, 45.3us). setprio around MFMA clusters.
// ---------------------------------------------------------------------------
constexpr int PRS = 72;

__global__ __launch_bounds__(512, 4) void attn_mfma(
    const unsigned short* __restrict__ qb,
    const unsigned short* __restrict__ kb,
    const unsigned short* __restrict__ vt,
    float* __restrict__ cacc0, float* __restrict__ cacc1,
    float* __restrict__ lbuf)
{
    __shared__ unsigned short Ks[2][64 * 64];
    __shared__ unsigned short Vs[2][64 * 64];
    __shared__ unsigned short Pt[8][32 * PRS];

    const int tid = threadIdx.x, w = tid >> 6, lane = tid & 63;
    const int lo = lane & 15, quad = lane >> 4;
    const int bid = blockIdx.x;                 // 0..511
    const int xcd = bid & 7;
    const int tt  = bid >> 3;                   // 0..63
    const int qgrp = tt & 7;                    // 0..7
    const int bhk  = (tt >> 3) * 8 + xcd;       // 0..63, same for 8 qgrps
    const int bh = bhk >> 1, ksp = bhk & 1;
    const int b = bh >> 4, h = bh & 15;
    const int q0 = qgrp * 256 + w * 32;

    short8 qf[2][2];
    #pragma unroll
    for (int qt = 0; qt < 2; ++qt) {
        const unsigned short* qrow =
            qb + (size_t)(b * NS + q0 + qt * 16 + lo) * ND + h * NDK + quad * 8;
        qf[qt][0] = *(const short8*)(qrow);
        qf[qt][1] = *(const short8*)(qrow + 32);
    }

    // staging: 64-row x 128B tiles = 512 x 16B chunks, 1 K + 1 V per thread.
    // LDS pos p of row r holds global chunk p ^ (r&7).
    const int r0 = tid >> 3, g0 = (tid & 7) ^ (r0 & 7);
    const unsigned short* Ksrc = kb + (size_t)(b * NS + r0) * ND + h * NDK + g0 * 8;
    const unsigned short* Vsrc = vt + (size_t)(bh * NDK + r0) * NS + g0 * 8;

#define STAGE(bf_, k_) { \
    GLOAD_LDS16(Ksrc + (size_t)(k_) * ND, &Ks[bf_][tid * 8]); \
    GLOAD_LDS16(Vsrc + (k_),              &Vs[bf_][tid * 8]); }

    floatx4 acc[2][4], lacc[2];
    #pragma unroll
    for (int qt = 0; qt < 2; ++qt) {
        lacc[qt] = (floatx4){0.f, 0.f, 0.f, 0.f};
        #pragma unroll
        for (int cb = 0; cb < 4; ++cb) acc[qt][cb] = (floatx4){0.f, 0.f, 0.f, 0.f};
    }

    const short8 ones = {0x3F80, 0x3F80, 0x3F80, 0x3F80,
                         0x3F80, 0x3F80, 0x3F80, 0x3F80};
    unsigned short* pw = &Pt[w][0];
    const int pos0 = (quad ^ (lo & 7)) * 8;
    const int pos1 = ((4 + quad) ^ (lo & 7)) * 8;

    const int kbase = ksp * 1024;
    STAGE(0, kbase);

    #pragma unroll 2
    for (int it = 0; it < 16; ++it) {
        const int bf = it & 1;
        if (it < 15) {
            STAGE(bf ^ 1, kbase + (it + 1) * 64);   // issue-early, depth-1
            asm volatile("s_waitcnt vmcnt(2)" ::: "memory");  // tile it landed
        } else {
            asm volatile("s_waitcnt vmcnt(0)" ::: "memory");
        }
        __builtin_amdgcn_s_barrier();
        __builtin_amdgcn_sched_barrier(0);

        const unsigned short* Kc = Ks[bf];
        const unsigned short* Vc = Vs[bf];

        // S^T = K @ Q^T : lane holds S^T[key=t*16+quad*4+r][q=lo]
        floatx4 s[2][4];
        __builtin_amdgcn_s_setprio(1);
        #pragma unroll
        for (int t = 0; t < 4; ++t) {
            const int rw = (t * 16 + lo) * 64;
            const short8 kf0 = *(const short8*)(Kc + rw + pos0);
            const short8 kf1 = *(const short8*)(Kc + rw + pos1);
            #pragma unroll
            for (int qt = 0; qt < 2; ++qt) {
                s[qt][t] = __builtin_amdgcn_mfma_f32_16x16x32_bf16(
                    kf0, qf[qt][0], (floatx4){0.f, 0.f, 0.f, 0.f}, 0, 0, 0);
                s[qt][t] = __builtin_amdgcn_mfma_f32_16x16x32_bf16(
                    kf1, qf[qt][1], s[qt][t], 0, 0, 0);
            }
        }
        __builtin_amdgcn_s_setprio(0);

        // P = exp2(s); truncating bf16 pack (bias cancels in O/l ratio)
        #pragma unroll
        for (int qt = 0; qt < 2; ++qt)
            #pragma unroll
            for (int t = 0; t < 4; ++t) {
                unsigned u0 = __builtin_bit_cast(unsigned, __builtin_amdgcn_exp2f(s[qt][t][0]));
                unsigned u1 = __builtin_bit_cast(unsigned, __builtin_amdgcn_exp2f(s[qt][t][1]));
                unsigned u2 = __builtin_bit_cast(unsigned, __builtin_amdgcn_exp2f(s[qt][t][2]));
                unsigned u3 = __builtin_bit_cast(unsigned, __builtin_amdgcn_exp2f(s[qt][t][3]));
                uint2 pk = {(u0 >> 16) | (u1 & 0xFFFF0000u),
                            (u2 >> 16) | (u3 & 0xFFFF0000u)};
                *(uint2*)(pw + (qt * 16 + lo) * PRS + t * 16 + quad * 4) = pk;
            }

        short8 pf[2][2];
        #pragma unroll
        for (int qt = 0; qt < 2; ++qt) {
            pf[qt][0] = *(const short8*)(pw + (qt * 16 + lo) * PRS + quad * 8);
            pf[qt][1] = *(const short8*)(pw + (qt * 16 + lo) * PRS + 32 + quad * 8);
            lacc[qt] = __builtin_amdgcn_mfma_f32_16x16x32_bf16(pf[qt][0], ones, lacc[qt], 0, 0, 0);
            lacc[qt] = __builtin_amdgcn_mfma_f32_16x16x32_bf16(pf[qt][1], ones, lacc[qt], 0, 0, 0);
        }

        __builtin_amdgcn_s_setprio(1);
        #pragma unroll
        for (int cb = 0; cb < 4; ++cb) {
            const int rw = (cb * 16 + lo) * 64;
            const short8 vf0 = *(const short8*)(Vc + rw + pos0);
            const short8 vf1 = *(const short8*)(Vc + rw + pos1);
            #pragma unroll
            for (int qt = 0; qt < 2; ++qt) {
                acc[qt][cb] = __builtin_amdgcn_mfma_f32_16x16x32_bf16(pf[qt][0], vf0, acc[qt][cb], 0, 0, 0);
                acc[qt][cb] = __builtin_amdgcn_mfma_f32_16x16x32_bf16(pf[qt][1], vf1, acc[qt][cb], 0, 0, 0);
            }
        }
        __builtin_amdgcn_s_setprio(0);

        __builtin_amdgcn_sched_barrier(0);
        __builtin_amdgcn_s_barrier();   // seal buf bf before restage at it+1
    }
#undef STAGE

    float* ca = ksp ? cacc1 : cacc0;
    float* lb = lbuf + (size_t)ksp * (NB * NH * NS);
    #pragma unroll
    for (int qt = 0; qt < 2; ++qt) {
        #pragma unroll
        for (int cb = 0; cb < 4; ++cb)
            #pragma unroll
            for (int r = 0; r < 4; ++r) {
                size_t off = (size_t)(b * NS + q0 + qt * 16 + quad * 4 + r) * ND
                           + h * NDK + cb * 16 + lo;
                ca[off] = acc[qt][cb][r];
            }
        if (lo == 0)
            #pragma unroll
            for (int r = 0; r < 4; ++r)
                lb[(size_t)bh * NS + q0 + qt * 16 + quad * 4 + r] = lacc[qt][r];
    }
}

// ---------------------------------------------------------------------------
// Output projection with fused softmax-divide — depth-1 pipelined (R8).
// ---------------------------------------------------------------------------
__global__ __launch_bounds__(256) void gemm_o(
    const float* __restrict__ cacc0, const float* __restrict__ cacc1,
    const float* __restrict__ lbuf, const unsigned short* __restrict__ Bw,
    const float* __restrict__ bias, float* __restrict__ Cout)
{
    __shared__ unsigned short As[64 * 64];
    __shared__ unsigned short Bs[2][128 * 64];
    const int tid = threadIdx.x, w = tid >> 6, lane = tid & 63;
    const int lo = lane & 15, quad = lane >> 4;
    const int bid = blockIdx.x;                // 0..511
    const int xcd = bid & 7;
    const int tt  = bid >> 3;                  // 0..63
    const int bn  = tt & 7;
    const int bm  = (tt >> 3) * 8 + xcd;       // 8 bn-blocks of same bm share XCD
    const int K = ND;
    const int wm = (w >> 1) * 32, wn = (w & 1) * 64;
    const size_t LHALF = (size_t)NB * NH * NS;

    const int ar = tid >> 3;
    const int ag = (tid & 7) ^ (ar & 7);
    const int tok0 = bm * 64 + ar, tok1 = tok0 + 32;
    const float* A00 = cacc0 + (size_t)tok0 * ND + ag * 8;
    const float* A01 = cacc1 + (size_t)tok0 * ND + ag * 8;
    const float* A10 = cacc0 + (size_t)tok1 * ND + ag * 8;
    const float* A11 = cacc1 + (size_t)tok1 * ND + ag * 8;
    const size_t lb0 = (size_t)((tok0 >> 11) << 4) * NS + (tok0 & (NS - 1));
    const size_t lb1 = (size_t)((tok1 >> 11) << 4) * NS + (tok1 & (NS - 1));
    unsigned short* AsD0 = As + tid * 8;
    unsigned short* AsD1 = As + (tid + 256) * 8;

    const unsigned short* Bg[4];
    int bsoff[4];
    #pragma unroll
    for (int p = 0; p < 4; ++p) {
        int c = tid + 256 * p, r = c >> 3, g = (c & 7) ^ (r & 7);
        Bg[p] = Bw + (size_t)(bn * 128 + r) * K + g * 8;
        bsoff[p] = c * 8;
    }

    floatx4 acc[2][4];
    #pragma unroll
    for (int i = 0; i < 2; ++i)
        #pragma unroll
        for (int j = 0; j < 4; ++j) acc[i][j] = (floatx4){0.f, 0.f, 0.f, 0.f};

    // prologue: stage B(tile0) -> Bs[0]; prefetch first A tile + l values
    #pragma unroll
    for (int p = 0; p < 4; ++p) GLOAD_LDS16(Bg[p], &Bs[0][bsoff[p]]);

    float4 ra[8];
    float lv0, lv1;
    ra[0] = *(const float4*)(A00);     ra[1] = *(const float4*)(A00 + 4);
    ra[2] = *(const float4*)(A01);     ra[3] = *(const float4*)(A01 + 4);
    ra[4] = *(const float4*)(A10);     ra[5] = *(const float4*)(A10 + 4);
    ra[6] = *(const float4*)(A11);     ra[7] = *(const float4*)(A11 + 4);
    lv0 = lbuf[lb0] + lbuf[lb0 + LHALF];
    lv1 = lbuf[lb1] + lbuf[lb1 + LHALF];

    #pragma unroll 1
    for (int t = 0; t < 16; ++t) {
        const int k0 = t * 64;
        const int cur = t & 1;
        // stage next B tile (depth-1, stays in flight through this iter)
        if (t < 15) {
            #pragma unroll
            for (int p = 0; p < 4; ++p)
                GLOAD_LDS16(Bg[p] + k0 + 64, &Bs[cur ^ 1][bsoff[p]]);
        }
        const float inv0 = __builtin_amdgcn_rcpf(lv0);
        const float inv1 = __builtin_amdgcn_rcpf(lv1);
        // wait: ra(t)+lv(t)+B(t) landed; only B(t+1) (4 loads) outstanding
        if (t < 15) asm volatile("s_waitcnt vmcnt(4)" ::: "memory");
        else        asm volatile("s_waitcnt vmcnt(0)" ::: "memory");
        __builtin_amdgcn_s_barrier();          // all waves' B(t) in LDS
        __builtin_amdgcn_sched_barrier(0);

        // pack A(t) -> As (single buffer; prior reads sealed by barrier3(t-1))
        {
            float4 s0 = {(ra[0].x + ra[2].x) * inv0, (ra[0].y + ra[2].y) * inv0,
                         (ra[0].z + ra[2].z) * inv0, (ra[0].w + ra[2].w) * inv0};
            float4 s1 = {(ra[1].x + ra[3].x) * inv0, (ra[1].y + ra[3].y) * inv0,
                         (ra[1].z + ra[3].z) * inv0, (ra[1].w + ra[3].w) * inv0};
            *(uint4*)AsD0 = pack8(s0, s1);
            float4 s2 = {(ra[4].x + ra[6].x) * inv1, (ra[4].y + ra[6].y) * inv1,
                         (ra[4].z + ra[6].z) * inv1, (ra[4].w + ra[6].w) * inv1};
            float4 s3 = {(ra[5].x + ra[7].x) * inv1, (ra[5].y + ra[7].y) * inv1,
                         (ra[5].z + ra[7].z) * inv1, (ra[5].w + ra[7].w) * inv1};
            *(uint4*)AsD1 = pack8(s2, s3);
        }

        // prefetch A(t+1) + l(t+1) (overlaps MFMA below)
        if (t < 15) {
            const int kn = k0 + 64;
            ra[0] = *(const float4*)(A00 + kn); ra[1] = *(const float4*)(A00 + kn + 4);
            ra[2] = *(const float4*)(A01 + kn); ra[3] = *(const float4*)(A01 + kn + 4);
            ra[4] = *(const float4*)(A10 + kn); ra[5] = *(const float4*)(A10 + kn + 4);
            ra[6] = *(const float4*)(A11 + kn); ra[7] = *(const float4*)(A11 + kn + 4);
            const size_t hoff = (size_t)(kn >> 6) * NS;
            lv0 = lbuf[lb0 + hoff] + lbuf[lb0 + hoff + LHALF];
            lv1 = lbuf[lb1 + hoff] + lbuf[lb1 + hoff + LHALF];
        }

        asm volatile("s_waitcnt lgkmcnt(0)" ::: "memory");  // own packs done
        __builtin_amdgcn_sched_barrier(0);
        __builtin_amdgcn_s_barrier();          // all packs visible

        __builtin_amdgcn_s_setprio(1);
        #pragma unroll
        for (int s = 0; s < 2; ++s) {
            const int pos = ((s * 4 + quad) ^ (lo & 7)) * 8;
            short8 af[2], bf[4];
            #pragma unroll
            for (int i = 0; i < 2; ++i)
                af[i] = *(const short8*)(As + (wm + i * 16 + lo) * 64 + pos);
            #pragma unroll
            for (int j = 0; j < 4; ++j)
                bf[j] = *(const short8*)(&Bs[cur][(wn + j * 16 + lo) * 64] + pos);
            #pragma unroll
            for (int i = 0; i < 2; ++i)
                #pragma unroll
                for (int j = 0; j < 4; ++j)
                    acc[i][j] = __builtin_amdgcn_mfma_f32_16x16x32_bf16(af[i], bf[j], acc[i][j], 0, 0, 0);
        }
        __builtin_amdgcn_s_setprio(0);
        __builtin_amdgcn_sched_barrier(0);
        __builtin_amdgcn_s_barrier();          // seal Bs[cur]/As reads
    }

    #pragma unroll
    for (int j = 0; j < 4; ++j) {
        const int col = bn * 128 + wn + j * 16 + lo;
        const float bb = bias[col];
        #pragma unroll
        for (int i = 0; i < 2; ++i)
            #pragma unroll
            for (int r = 0; r < 4; ++r) {
                const int row = bm * 64 + wm + i * 16 + quad * 4 + r;
                Cout[(size_t)row * ND + col] = acc[i][j][r] + bb;
            }
    }
}

// ---------------------------------------------------------------------------
extern "C" void kernel_launch(void* const* d_in, const int* in_sizes, int n_in,
                              void* d_out, int out_size, void* d_ws, size_t ws_size,
                              hipStream_t stream)
{
    const float* query = (const float*)d_in[0];
    const float* key   = (const float*)d_in[1];
    const float* value = (const float*)d_in[2];
    const float* Wq    = (const float*)d_in[3];
    const float* bq    = (const float*)d_in[4];
    const float* Wk    = (const float*)d_in[5];
    const float* bk    = (const float*)d_in[6];
    const float* Wv    = (const float*)d_in[7];
    const float* bv    = (const float*)d_in[8];
    const float* Wo    = (const float*)d_in[9];
    const float* bo    = (const float*)d_in[10];
    float* out = (float*)d_out;

    const size_t n  = (size_t)NB * NS * ND;   // 4,194,304
    const size_t nw = (size_t)ND * ND;        // 1,048,576

    unsigned short* X0   = (unsigned short*)d_ws;  // (unused, layout kept)
    unsigned short* X1   = X0 + n;                 // -> cacc0 (w/ X2)
    unsigned short* X2   = X1 + n;
    unsigned short* W0   = X2 + n;                 // (unused)
    unsigned short* W1   = W0 + nw;                // (unused)
    unsigned short* W2   = W1 + nw;                // (unused)
    unsigned short* W3   = W2 + nw;                // Wo bf16
    unsigned short* qbuf = W3 + nw;
    unsigned short* kbuf = qbuf + n;
    unsigned short* vtb  = kbuf + n;
    float* cacc1 = (float*)(vtb + n);              // n f32
    float* lbuf  = cacc1 + n;                      // 2 x NB*NH*NS f32
    float* cacc0 = (float*)X1;                     // n f32, overlays X1+X2

    cvt_w<<<512, 256, 0, stream>>>(Wo, W3);

    gemm_qkv<<<192, 512, 0, stream>>>(query, key, value, Wq, Wk, Wv,
                                      bq, bk, bv, qbuf, kbuf, vtb);

    attn_mfma<<<512, 512, 0, stream>>>(qbuf, kbuf, vtb, cacc0, cacc1, lbuf);

    gemm_o<<<512, 256, 0, stream>>>(cacc0, cacc1, lbuf, W3, bo, out);
}

// Round 11
// 216.961 us; speedup vs baseline: 1.8317x; 1.8317x over previous
//
#include <hip/hip_runtime.h>
#include <math.h>

constexpr int NB = 2;
constexpr int NS = 2048;
constexpr int ND = 1024;
constexpr int NH = 16;
constexpr int NDK = 64;

typedef __attribute__((ext_vector_type(8))) short short8;
typedef __attribute__((ext_vector_type(4))) float floatx4;

__device__ inline unsigned short f2bf(float x) {
    unsigned u = __builtin_bit_cast(unsigned, x);
    u += 0x7fffu + ((u >> 16) & 1u);          // RNE
    return (unsigned short)(u >> 16);
}

__device__ inline uint4 pack8(float4 a, float4 b) {
    unsigned short t[8] = {f2bf(a.x), f2bf(a.y), f2bf(a.z), f2bf(a.w),
                           f2bf(b.x), f2bf(b.y), f2bf(b.z), f2bf(b.w)};
    return *(uint4*)t;
}

#define GLOAD_LDS16(g, l) __builtin_amdgcn_global_load_lds( \
    (const __attribute__((address_space(1))) void*)(g),     \
    (__attribute__((address_space(3))) void*)(l), 16, 0, 0)

// scale folded into Q projection: exp(s/8) == exp2(s * 0.125 * log2(e))
#define QSCALE 0.18033688f

// ---------------------------------------------------------------------------
// single fused fp32 -> bf16 convert for all 7 tensors (blockIdx.y selects)
// ---------------------------------------------------------------------------
__global__ __launch_bounds__(256) void cvt_all(
    const float* __restrict__ s0, const float* __restrict__ s1,
    const float* __restrict__ s2, const float* __restrict__ s3,
    const float* __restrict__ s4, const float* __restrict__ s5,
    const float* __restrict__ s6,
    unsigned short* __restrict__ d0, unsigned short* __restrict__ d1,
    unsigned short* __restrict__ d2, unsigned short* __restrict__ d3,
    unsigned short* __restrict__ d4, unsigned short* __restrict__ d5,
    unsigned short* __restrict__ d6)
{
    const int y = blockIdx.y;
    const float* srcs[7] = {s0, s1, s2, s3, s4, s5, s6};
    unsigned short* dsts[7] = {d0, d1, d2, d3, d4, d5, d6};
    const int nel = (y < 3) ? NB * NS * ND : ND * ND;
    int i = (blockIdx.x * 256 + threadIdx.x) * 8;
    if (i >= nel) return;
    const float* s = srcs[y];
    unsigned short* d = dsts[y];
    float4 a = *(const float4*)(s + i);
    float4 b = *(const float4*)(s + i + 4);
    *(uint4*)(d + i) = pack8(a, b);
}

// ---------------------------------------------------------------------------
// Fused QKV projection — 256x256 tile, BK=64, 8-phase schedule (m201 template).
// global_load_lds staging (zero staging VGPRs — the template has no register
// headroom; R10's reg-staged f32 variant spilled acc to scratch).
// ---------------------------------------------------------------------------
template<int QA, int QB>
__device__ __forceinline__ void mfma_quad(
    floatx4 (&acc)[8][4], const short8 (&ta)[4][2], const short8 (&tb)[2][2][2])
{
#pragma unroll
    for (int ii = 0; ii < 4; ++ii)
#pragma unroll
        for (int jj = 0; jj < 2; ++jj) {
            acc[QA * 4 + ii][QB * 2 + jj] = __builtin_amdgcn_mfma_f32_16x16x32_bf16(
                ta[ii][0], tb[QB][jj][0], acc[QA * 4 + ii][QB * 2 + jj], 0, 0, 0);
            acc[QA * 4 + ii][QB * 2 + jj] = __builtin_amdgcn_mfma_f32_16x16x32_bf16(
                ta[ii][1], tb[QB][jj][1], acc[QA * 4 + ii][QB * 2 + jj], 0, 0, 0);
        }
}

__global__ __launch_bounds__(512, 2) void gemm_qkv(
    const unsigned short* __restrict__ Xq, const unsigned short* __restrict__ Xk,
    const unsigned short* __restrict__ Xv,
    const unsigned short* __restrict__ Wq, const unsigned short* __restrict__ Wk,
    const unsigned short* __restrict__ Wv,
    const float* __restrict__ bq, const float* __restrict__ bk,
    const float* __restrict__ bv,
    unsigned short* __restrict__ Cq, unsigned short* __restrict__ Ck,
    unsigned short* __restrict__ Cv)
{
    __shared__ unsigned short As[2][256 * 64];
    __shared__ unsigned short Bs[2][256 * 64];

    const int tid = threadIdx.x, w = tid >> 6, lane = tid & 63;
    const int lo = lane & 15, quad = lane >> 4;
    const int bid = blockIdx.x;
    const int seg = bid >> 6;          // 0,1,2 (64 blocks each)
    const int idx = bid & 63;
    const int xcd = idx & 7;
    const int t8  = idx >> 3;          // 0..7
    const int K = ND;

    int bm, bn;
    const unsigned short *A, *Bw;
    const float* bias;
    if (seg == 2) {
        bm = t8 & 3; bn = (t8 >> 2) * 8 + xcd;
        A = Wv; Bw = Xv; bias = bv;
    } else {
        bn = t8 & 3; bm = (t8 >> 2) * 8 + xcd;
        if (seg == 1) { A = Xk; Bw = Wk; bias = bk; }
        else          { A = Xq; Bw = Wq; bias = bq; }
    }

    const int WM = (w >> 2) * 128, WN = (w & 3) * 64;

    const int srow = tid >> 3;                               // 0..63
    const int sgo  = ((tid & 7) ^ (srow & 7)) * 8;           // element offset
    const unsigned short* Asrc = A  + (size_t)(bm * 256 + srow) * K + sgo;
    const unsigned short* Bsrc = Bw + (size_t)(bn * 256 + srow) * K + sgo;

#define SA(bf_, t_, s_) GLOAD_LDS16(Asrc + (size_t)(s_) * 64 * K + (t_) * 64, \
                                    &As[bf_][(s_) * 4096 + tid * 8])
#define SB(bf_, t_, s_) GLOAD_LDS16(Bsrc + (size_t)(s_) * 64 * K + (t_) * 64, \
                                    &Bs[bf_][(s_) * 4096 + tid * 8])

    const int rp0 = ((quad) ^ (lo & 7)) * 8;        // kstep 0 chunk pos
    const int rp1 = ((4 + quad) ^ (lo & 7)) * 8;    // kstep 1 chunk pos

    short8 ta[4][2], tb[2][2][2];

#define RDA(bf_, qa_) { _Pragma("unroll") \
    for (int ii = 0; ii < 4; ++ii) { \
        const unsigned short* p_ = &As[bf_][(WM + (qa_) * 64 + ii * 16 + lo) * 64]; \
        ta[ii][0] = *(const short8*)(p_ + rp0); \
        ta[ii][1] = *(const short8*)(p_ + rp1); } }
#define RDB(bf_, qb_) { _Pragma("unroll") \
    for (int jj = 0; jj < 2; ++jj) { \
        const unsigned short* p_ = &Bs[bf_][(WN + (qb_) * 32 + jj * 16 + lo) * 64]; \
        tb[qb_][jj][0] = *(const short8*)(p_ + rp0); \
        tb[qb_][jj][1] = *(const short8*)(p_ + rp1); } }

#define PH_SYNC1 __builtin_amdgcn_s_barrier(); \
    asm volatile("s_waitcnt lgkmcnt(0)" ::: "memory"); \
    __builtin_amdgcn_sched_barrier(0); \
    __builtin_amdgcn_s_setprio(1);
#define PH_SYNC2 __builtin_amdgcn_s_setprio(0); \
    __builtin_amdgcn_sched_barrier(0); \
    __builtin_amdgcn_s_barrier();

    floatx4 acc[8][4];
#pragma unroll
    for (int i = 0; i < 8; ++i)
#pragma unroll
        for (int j = 0; j < 4; ++j) acc[i][j] = (floatx4){0.f, 0.f, 0.f, 0.f};

    // prologue: B(buf0)<-t0, A(buf0)<-t0, B(buf1)<-t1  (12 loads)
    SB(0, 0, 0); SB(0, 0, 1); SB(0, 0, 2); SB(0, 0, 3);
    SA(0, 0, 0); SA(0, 0, 1); SA(0, 0, 2); SA(0, 0, 3);
    SB(1, 1, 0); SB(1, 1, 1); SB(1, 1, 2); SB(1, 1, 3);
    asm volatile("s_waitcnt vmcnt(4)" ::: "memory");   // t0 A+B landed
    __builtin_amdgcn_s_barrier();

    constexpr int NIT = ND / 128;   // 8 iterations, 2 K-tiles each
#pragma unroll 1
    for (int it = 0; it < NIT; ++it) {
        const bool nl = (it < NIT - 1);
        const int t1 = 2 * it + 1, t2 = 2 * it + 2, t3 = 2 * it + 3;

        // p0: buf0 quadrant (0,0); stage A(buf1)<-t1 slots 0,1
        RDA(0, 0); RDB(0, 0);
        SA(1, t1, 0); SA(1, t1, 1);
        PH_SYNC1; mfma_quad<0, 0>(acc, ta, tb); PH_SYNC2;

        // p1: buf0 (0,1); stage A(buf1)<-t1 slots 2,3
        RDB(0, 1);
        SA(1, t1, 2); SA(1, t1, 3);
        PH_SYNC1; mfma_quad<0, 1>(acc, ta, tb); PH_SYNC2;

        // p2: buf0 (1,1); stage B(buf0)<-t2 slots 0,1
        RDA(0, 1);
        if (nl) { SB(0, t2, 0); SB(0, t2, 1); }
        PH_SYNC1; mfma_quad<1, 1>(acc, ta, tb); PH_SYNC2;

        // p3: buf0 (1,0); stage B(buf0)<-t2 slots 2,3; counted wait for buf1
        if (nl) { SB(0, t2, 2); SB(0, t2, 3); }
        if (nl) asm volatile("s_waitcnt vmcnt(4)" ::: "memory");
        else    asm volatile("s_waitcnt vmcnt(0)" ::: "memory");
        PH_SYNC1; mfma_quad<1, 0>(acc, ta, tb); PH_SYNC2;

        // p4: buf1 (0,0); stage A(buf0)<-t2 slots 0,1
        RDA(1, 0); RDB(1, 0);
        if (nl) { SA(0, t2, 0); SA(0, t2, 1); }
        PH_SYNC1; mfma_quad<0, 0>(acc, ta, tb); PH_SYNC2;

        // p5: buf1 (0,1); stage A(buf0)<-t2 slots 2,3
        RDB(1, 1);
        if (nl) { SA(0, t2, 2); SA(0, t2, 3); }
        PH_SYNC1; mfma_quad<0, 1>(acc, ta, tb); PH_SYNC2;

        // p6: buf1 (1,1); stage B(buf1)<-t3 slots 0,1
        RDA(1, 1);
        if (nl) { SB(1, t3, 0); SB(1, t3, 1); }
        PH_SYNC1; mfma_quad<1, 1>(acc, ta, tb); PH_SYNC2;

        // p7: buf1 (1,0); stage B(buf1)<-t3 slots 2,3; counted wait for buf0
        if (nl) { SB(1, t3, 2); SB(1, t3, 3); }
        if (nl) asm volatile("s_waitcnt vmcnt(4)" ::: "memory");
        PH_SYNC1; mfma_quad<1, 0>(acc, ta, tb); PH_SYNC2;
    }

#undef SA
#undef SB
#undef RDA
#undef RDB
#undef PH_SYNC1
#undef PH_SYNC2

    if (seg < 2) {
        unsigned short* C = seg ? Ck : Cq;
        const float scale = seg ? 1.f : QSCALE;
#pragma unroll
        for (int j = 0; j < 4; ++j) {
            const int col = bn * 256 + WN + j * 16 + lo;
            const float bb = bias[col];
#pragma unroll
            for (int i = 0; i < 8; ++i)
#pragma unroll
                for (int r = 0; r < 4; ++r) {
                    const int row = bm * 256 + WM + i * 16 + quad * 4 + r;
                    C[(size_t)row * ND + col] = f2bf((acc[i][j][r] + bb) * scale);
                }
        }
    } else {
#pragma unroll
        for (int i = 0; i < 8; ++i)
#pragma unroll
            for (int r = 0; r < 4; ++r) {
                const int row = bm * 256 + WM + i * 16 + quad * 4 + r;
                const float bb = bias[row];
#pragma unroll
                for (int j = 0; j < 4; ++j) {
                    const int col = bn * 256 + WN + j * 16 + lo;
                    const int b = col >> 11, s = col & (NS - 1);
                    Cv[(size_t)(b * ND + row) * NS + s] = f2bf(acc[i][j][r] + bb);
                }
            }
    }
}

// ---------------------------------------------------------------------------
// MFMA flash attention, K-split x2. 512 threads = 8 waves, 256 q-rows/block,
// grid 512 = 2 blocks/CU. TRIPLE-buffered K/V, ONE barrier per iteration,
// vmcnt(2), Pt XOR-swizzle (verified R9: 218.4us total, conflicts 2.1M).
// ---------------------------------------------------------------------------
__global__ __launch_bounds__(512, 4) void attn_mfma(
    const unsigned short* __restrict__ qb,
    const unsigned short* __restrict__ kb,
    const unsigned short* __restrict__ vt,
    float* __restrict__ cacc0, float* __restrict__ cacc1,
    float* __restrict__ lbuf)
{
    __shared__ unsigned short Ks[3][64 * 64];   // 24 KB
    __shared__ unsigned short Vs[3][64 * 64];   // 24 KB
    __shared__ unsigned short Pt[8][32 * 64];   // 32 KB  (XOR-swizzled rows)

    const int tid = threadIdx.x, w = tid >> 6, lane = tid & 63;
    const int lo = lane & 15, quad = lane >> 4;
    const int bid = blockIdx.x;                 // 0..511
    const int xcd = bid & 7;
    const int tt  = bid >> 3;                   // 0..63
    const int qgrp = tt & 7;                    // 0..7
    const int bhk  = (tt >> 3) * 8 + xcd;       // 0..63, same for 8 qgrps
    const int bh = bhk >> 1, ksp = bhk & 1;
    const int b = bh >> 4, h = bh & 15;
    const int q0 = qgrp * 256 + w * 32;

    short8 qf[2][2];
    #pragma unroll
    for (int qt = 0; qt < 2; ++qt) {
        const unsigned short* qrow =
            qb + (size_t)(b * NS + q0 + qt * 16 + lo) * ND + h * NDK + quad * 8;
        qf[qt][0] = *(const short8*)(qrow);
        qf[qt][1] = *(const short8*)(qrow + 32);
    }

    // staging: 64-row x 128B tiles = 512 x 16B chunks, 1 K + 1 V per thread.
    // LDS pos p of row r holds global chunk p ^ (r&7).
    const int r0 = tid >> 3, g0 = (tid & 7) ^ (r0 & 7);
    const unsigned short* Ksrc = kb + (size_t)(b * NS + r0) * ND + h * NDK + g0 * 8;
    const unsigned short* Vsrc = vt + (size_t)(bh * NDK + r0) * NS + g0 * 8;
    unsigned short* Ks0 = &Ks[0][0];
    unsigned short* Vs0 = &Vs[0][0];

#define STAGE(bi_, k_) { \
    GLOAD_LDS16(Ksrc + (size_t)(k_) * ND, Ks0 + (bi_) * 4096 + tid * 8); \
    GLOAD_LDS16(Vsrc + (k_),              Vs0 + (bi_) * 4096 + tid * 8); }

    floatx4 acc[2][4], lacc[2];
    #pragma unroll
    for (int qt = 0; qt < 2; ++qt) {
        lacc[qt] = (floatx4){0.f, 0.f, 0.f, 0.f};
        #pragma unroll
        for (int cb = 0; cb < 4; ++cb) acc[qt][cb] = (floatx4){0.f, 0.f, 0.f, 0.f};
    }

    const short8 ones = {0x3F80, 0x3F80, 0x3F80, 0x3F80,
                         0x3F80, 0x3F80, 0x3F80, 0x3F80};
    unsigned short* pw = &Pt[w][0];
    const int pos0 = (quad ^ (lo & 7)) * 8;
    const int pos1 = ((4 + quad) ^ (lo & 7)) * 8;
    const int pxor = (lo & 7) << 3;             // Pt store elem-offset XOR

    const int kbase = ksp * 1024;
    STAGE(0, kbase);
    STAGE(1, kbase + 64);

    int rd = 0, wr = 2;
    #pragma unroll 1
    for (int it = 0; it < 16; ++it) {
        if (it < 15) asm volatile("s_waitcnt vmcnt(2)" ::: "memory");
        else         asm volatile("s_waitcnt vmcnt(0)" ::: "memory");
        __builtin_amdgcn_s_barrier();           // data(tile it) + seal(it-1 reads)
        __builtin_amdgcn_sched_barrier(0);
        if (it < 14) STAGE(wr, kbase + (it + 2) * 64);

        const unsigned short* Kc = Ks0 + rd * 4096;
        const unsigned short* Vc = Vs0 + rd * 4096;

        // S^T = K @ Q^T : lane holds S^T[key=t*16+quad*4+r][q=lo]
        floatx4 s[2][4];
        __builtin_amdgcn_s_setprio(1);
        #pragma unroll
        for (int t = 0; t < 4; ++t) {
            const int rw = (t * 16 + lo) * 64;
            const short8 kf0 = *(const short8*)(Kc + rw + pos0);
            const short8 kf1 = *(const short8*)(Kc + rw + pos1);
            #pragma unroll
            for (int qt = 0; qt < 2; ++qt) {
                s[qt][t] = __builtin_amdgcn_mfma_f32_16x16x32_bf16(
                    kf0, qf[qt][0], (floatx4){0.f, 0.f, 0.f, 0.f}, 0, 0, 0);
                s[qt][t] = __builtin_amdgcn_mfma_f32_16x16x32_bf16(
                    kf1, qf[qt][1], s[qt][t], 0, 0, 0);
            }
        }
        __builtin_amdgcn_s_setprio(0);

        // P = exp2(s); truncating bf16 pack (bias cancels in O/l ratio).
        // Store at XOR-swizzled elem offset (t*16+quad*4) ^ pxor.
        #pragma unroll
        for (int qt = 0; qt < 2; ++qt)
            #pragma unroll
            for (int t = 0; t < 4; ++t) {
                unsigned u0 = __builtin_bit_cast(unsigned, __builtin_amdgcn_exp2f(s[qt][t][0]));
                unsigned u1 = __builtin_bit_cast(unsigned, __builtin_amdgcn_exp2f(s[qt][t][1]));
                unsigned u2 = __builtin_bit_cast(unsigned, __builtin_amdgcn_exp2f(s[qt][t][2]));
                unsigned u3 = __builtin_bit_cast(unsigned, __builtin_amdgcn_exp2f(s[qt][t][3]));
                uint2 pk = {(u0 >> 16) | (u1 & 0xFFFF0000u),
                            (u2 >> 16) | (u3 & 0xFFFF0000u)};
                *(uint2*)(pw + (qt * 16 + lo) * 64 + ((t * 16 + quad * 4) ^ pxor)) = pk;
            }

        short8 pf[2][2];
        #pragma unroll
        for (int qt = 0; qt < 2; ++qt) {
            pf[qt][0] = *(const short8*)(pw + (qt * 16 + lo) * 64 + pos0);
            pf[qt][1] = *(const short8*)(pw + (qt * 16 + lo) * 64 + pos1);
            lacc[qt] = __builtin_amdgcn_mfma_f32_16x16x32_bf16(pf[qt][0], ones, lacc[qt], 0, 0, 0);
            lacc[qt] = __builtin_amdgcn_mfma_f32_16x16x32_bf16(pf[qt][1], ones, lacc[qt], 0, 0, 0);
        }

        __builtin_amdgcn_s_setprio(1);
        #pragma unroll
        for (int cb = 0; cb < 4; ++cb) {
            const int rw = (cb * 16 + lo) * 64;
            const short8 vf0 = *(const short8*)(Vc + rw + pos0);
            const short8 vf1 = *(const short8*)(Vc + rw + pos1);
            #pragma unroll
            for (int qt = 0; qt < 2; ++qt) {
                acc[qt][cb] = __builtin_amdgcn_mfma_f32_16x16x32_bf16(pf[qt][0], vf0, acc[qt][cb], 0, 0, 0);
                acc[qt][cb] = __builtin_amdgcn_mfma_f32_16x16x32_bf16(pf[qt][1], vf1, acc[qt][cb], 0, 0, 0);
            }
        }
        __builtin_amdgcn_s_setprio(0);

        rd = (rd == 2) ? 0 : rd + 1;
        wr = (wr == 2) ? 0 : wr + 1;
    }
#undef STAGE

    float* ca = ksp ? cacc1 : cacc0;
    float* lb = lbuf + (size_t)ksp * (NB * NH * NS);
    #pragma unroll
    for (int qt = 0; qt < 2; ++qt) {
        #pragma unroll
        for (int cb = 0; cb < 4; ++cb)
            #pragma unroll
            for (int r = 0; r < 4; ++r) {
                size_t off = (size_t)(b * NS + q0 + qt * 16 + quad * 4 + r) * ND
                           + h * NDK + cb * 16 + lo;
                ca[off] = acc[qt][cb][r];
            }
        if (lo == 0)
            #pragma unroll
            for (int r = 0; r < 4; ++r)
                lb[(size_t)bh * NS + q0 + qt * 16 + quad * 4 + r] = lacc[qt][r];
    }
}

// ---------------------------------------------------------------------------
// Output projection with fused softmax-divide — depth-1 pipelined (R8).
// ---------------------------------------------------------------------------
__global__ __launch_bounds__(256) void gemm_o(
    const float* __restrict__ cacc0, const float* __restrict__ cacc1,
    const float* __restrict__ lbuf, const unsigned short* __restrict__ Bw,
    const float* __restrict__ bias, float* __restrict__ Cout)
{
    __shared__ unsigned short As[64 * 64];
    __shared__ unsigned short Bs[2][128 * 64];
    const int tid = threadIdx.x, w = tid >> 6, lane = tid & 63;
    const int lo = lane & 15, quad = lane >> 4;
    const int bid = blockIdx.x;                // 0..511
    const int xcd = bid & 7;
    const int tt  = bid >> 3;                  // 0..63
    const int bn  = tt & 7;
    const int bm  = (tt >> 3) * 8 + xcd;       // 8 bn-blocks of same bm share XCD
    const int K = ND;
    const int wm = (w >> 1) * 32, wn = (w & 1) * 64;
    const size_t LHALF = (size_t)NB * NH * NS;

    const int ar = tid >> 3;
    const int ag = (tid & 7) ^ (ar & 7);
    const int tok0 = bm * 64 + ar, tok1 = tok0 + 32;
    const float* A00 = cacc0 + (size_t)tok0 * ND + ag * 8;
    const float* A01 = cacc1 + (size_t)tok0 * ND + ag * 8;
    const float* A10 = cacc0 + (size_t)tok1 * ND + ag * 8;
    const float* A11 = cacc1 + (size_t)tok1 * ND + ag * 8;
    const size_t lb0 = (size_t)((tok0 >> 11) << 4) * NS + (tok0 & (NS - 1));
    const size_t lb1 = (size_t)((tok1 >> 11) << 4) * NS + (tok1 & (NS - 1));
    unsigned short* AsD0 = As + tid * 8;
    unsigned short* AsD1 = As + (tid + 256) * 8;

    const unsigned short* Bg[4];
    int bsoff[4];
    #pragma unroll
    for (int p = 0; p < 4; ++p) {
        int c = tid + 256 * p, r = c >> 3, g = (c & 7) ^ (r & 7);
        Bg[p] = Bw + (size_t)(bn * 128 + r) * K + g * 8;
        bsoff[p] = c * 8;
    }

    floatx4 acc[2][4];
    #pragma unroll
    for (int i = 0; i < 2; ++i)
        #pragma unroll
        for (int j = 0; j < 4; ++j) acc[i][j] = (floatx4){0.f, 0.f, 0.f, 0.f};

    // prologue: stage B(tile0) -> Bs[0]; prefetch first A tile + l values
    #pragma unroll
    for (int p = 0; p < 4; ++p) GLOAD_LDS16(Bg[p], &Bs[0][bsoff[p]]);

    float4 ra[8];
    float lv0, lv1;
    ra[0] = *(const float4*)(A00);     ra[1] = *(const float4*)(A00 + 4);
    ra[2] = *(const float4*)(A01);     ra[3] = *(const float4*)(A01 + 4);
    ra[4] = *(const float4*)(A10);     ra[5] = *(const float4*)(A10 + 4);
    ra[6] = *(const float4*)(A11);     ra[7] = *(const float4*)(A11 + 4);
    lv0 = lbuf[lb0] + lbuf[lb0 + LHALF];
    lv1 = lbuf[lb1] + lbuf[lb1 + LHALF];

    #pragma unroll 1
    for (int t = 0; t < 16; ++t) {
        const int k0 = t * 64;
        const int cur = t & 1;
        // stage next B tile (depth-1, stays in flight through this iter)
        if (t < 15) {
            #pragma unroll
            for (int p = 0; p < 4; ++p)
                GLOAD_LDS16(Bg[p] + k0 + 64, &Bs[cur ^ 1][bsoff[p]]);
        }
        const float inv0 = __builtin_amdgcn_rcpf(lv0);
        const float inv1 = __builtin_amdgcn_rcpf(lv1);
        // wait: ra(t)+lv(t)+B(t) landed; only B(t+1) (4 loads) outstanding
        if (t < 15) asm volatile("s_waitcnt vmcnt(4)" ::: "memory");
        else        asm volatile("s_waitcnt vmcnt(0)" ::: "memory");
        __builtin_amdgcn_s_barrier();          // all waves' B(t) in LDS
        __builtin_amdgcn_sched_barrier(0);

        // pack A(t) -> As (single buffer; prior reads sealed by barrier3(t-1))
        {
            float4 s0 = {(ra[0].x + ra[2].x) * inv0, (ra[0].y + ra[2].y) * inv0,
                         (ra[0].z + ra[2].z) * inv0, (ra[0].w + ra[2].w) * inv0};
            float4 s1 = {(ra[1].x + ra[3].x) * inv0, (ra[1].y + ra[3].y) * inv0,
                         (ra[1].z + ra[3].z) * inv0, (ra[1].w + ra[3].w) * inv0};
            *(uint4*)AsD0 = pack8(s0, s1);
            float4 s2 = {(ra[4].x + ra[6].x) * inv1, (ra[4].y + ra[6].y) * inv1,
                         (ra[4].z + ra[6].z) * inv1, (ra[4].w + ra[6].w) * inv1};
            float4 s3 = {(ra[5].x + ra[7].x) * inv1, (ra[5].y + ra[7].y) * inv1,
                         (ra[5].z + ra[7].z) * inv1, (ra[5].w + ra[7].w) * inv1};
            *(uint4*)AsD1 = pack8(s2, s3);
        }

        // prefetch A(t+1) + l(t+1) (overlaps MFMA below)
        if (t < 15) {
            const int kn = k0 + 64;
            ra[0] = *(const float4*)(A00 + kn); ra[1] = *(const float4*)(A00 + kn + 4);
            ra[2] = *(const float4*)(A01 + kn); ra[3] = *(const float4*)(A01 + kn + 4);
            ra[4] = *(const float4*)(A10 + kn); ra[5] = *(const float4*)(A10 + kn + 4);
            ra[6] = *(const float4*)(A11 + kn); ra[7] = *(const float4*)(A11 + kn + 4);
            const size_t hoff = (size_t)(kn >> 6) * NS;
            lv0 = lbuf[lb0 + hoff] + lbuf[lb0 + hoff + LHALF];
            lv1 = lbuf[lb1 + hoff] + lbuf[lb1 + hoff + LHALF];
        }

        asm volatile("s_waitcnt lgkmcnt(0)" ::: "memory");  // own packs done
        __builtin_amdgcn_sched_barrier(0);
        __builtin_amdgcn_s_barrier();          // all packs visible

        __builtin_amdgcn_s_setprio(1);
        #pragma unroll
        for (int s = 0; s < 2; ++s) {
            const int pos = ((s * 4 + quad) ^ (lo & 7)) * 8;
            short8 af[2], bf[4];
            #pragma unroll
            for (int i = 0; i < 2; ++i)
                af[i] = *(const short8*)(As + (wm + i * 16 + lo) * 64 + pos);
            #pragma unroll
            for (int j = 0; j < 4; ++j)
                bf[j] = *(const short8*)(&Bs[cur][(wn + j * 16 + lo) * 64] + pos);
            #pragma unroll
            for (int i = 0; i < 2; ++i)
                #pragma unroll
                for (int j = 0; j < 4; ++j)
                    acc[i][j] = __builtin_amdgcn_mfma_f32_16x16x32_bf16(af[i], bf[j], acc[i][j], 0, 0, 0);
        }
        __builtin_amdgcn_s_setprio(0);
        __builtin_amdgcn_sched_barrier(0);
        __builtin_amdgcn_s_barrier();          // seal Bs[cur]/As reads
    }

    #pragma unroll
    for (int j = 0; j < 4; ++j) {
        const int col = bn * 128 + wn + j * 16 + lo;
        const float bb = bias[col];
        #pragma unroll
        for (int i = 0; i < 2; ++i)
            #pragma unroll
            for (int r = 0; r < 4; ++r) {
                const int row = bm * 64 + wm + i * 16 + quad * 4 + r;
                Cout[(size_t)row * ND + col] = acc[i][j][r] + bb;
            }
    }
}

// ---------------------------------------------------------------------------
extern "C" void kernel_launch(void* const* d_in, const int* in_sizes, int n_in,
                              void* d_out, int out_size, void* d_ws, size_t ws_size,
                              hipStream_t stream)
{
    const float* query = (const float*)d_in[0];
    const float* key   = (const float*)d_in[1];
    const float* value = (const float*)d_in[2];
    const float* Wq    = (const float*)d_in[3];
    const float* bq    = (const float*)d_in[4];
    const float* Wk    = (const float*)d_in[5];
    const float* bk    = (const float*)d_in[6];
    const float* Wv    = (const float*)d_in[7];
    const float* bv    = (const float*)d_in[8];
    const float* Wo    = (const float*)d_in[9];
    const float* bo    = (const float*)d_in[10];
    float* out = (float*)d_out;

    const size_t n  = (size_t)NB * NS * ND;   // 4,194,304
    const size_t nw = (size_t)ND * ND;        // 1,048,576

    unsigned short* X0   = (unsigned short*)d_ws;  // query bf16
    unsigned short* X1   = X0 + n;                 // key bf16   -> cacc0 (w/ X2)
    unsigned short* X2   = X1 + n;                 // value bf16
    unsigned short* W0   = X2 + n;
    unsigned short* W1   = W0 + nw;
    unsigned short* W2   = W1 + nw;
    unsigned short* W3   = W2 + nw;
    unsigned short* qbuf = W3 + nw;
    unsigned short* kbuf = qbuf + n;
    unsigned short* vtb  = kbuf + n;
    float* cacc1 = (float*)(vtb + n);              // n f32
    float* lbuf  = cacc1 + n;                      // 2 x NB*NH*NS f32
    float* cacc0 = (float*)X1;                     // n f32, overlays X1+X2

    cvt_all<<<dim3((int)(n / 2048), 7), 256, 0, stream>>>(
        query, key, value, Wq, Wk, Wv, Wo, X0, X1, X2, W0, W1, W2, W3);

    gemm_qkv<<<192, 512, 0, stream>>>(X0, X1, X2, W0, W1, W2,
                                      bq, bk, bv, qbuf, kbuf, vtb);

    attn_mfma<<<512, 512, 0, stream>>>(qbuf, kbuf, vtb, cacc0, cacc1, lbuf);

    gemm_o<<<512, 256, 0, stream>>>(cacc0, cacc1, lbuf, W3, bo, out);
}